// Round 9
// baseline (106.910 us; speedup 1.0000x reference)
//
#include <hip/hip_runtime.h>
#include <cstddef>

#define NWALKS 16384
#define TLEN   20
#define HDIM   128
#define WPB    32     // walks per block (2 tiles of 16)
#define NTHR   256    // 4 waves, each owning 32 j-columns

typedef __attribute__((ext_vector_type(8))) _Float16 f16x8;
typedef __attribute__((ext_vector_type(4))) _Float16 f16x4;
typedef __attribute__((ext_vector_type(2))) __fp16   h16x2;   // cvt_pkrtz result type
typedef __attribute__((ext_vector_type(4))) float    f32x4;

union H4 { f16x4 v; struct { h16x2 lo, hi; } p; };
union H8 { f16x8 v; struct { h16x2 a, b, c, d; } p; };

// ---------------------------------------------------------------------------
// fold: Wc16 = f16(scale_row * (W_ih @ W_f)), Whh16 = f16(scale_row * W_hh),
// b_c = W_ih@b_f + b_ih (unscaled; scaled at load in gru_kernel).
//   r,z rows (0..255):  * -log2(e)   -> sigmoid(v) = rcp(1 + exp2(acc))
//   n  rows (256..383): * +2*log2(e) -> tanh(v)    = 1 - 2*rcp(exp2(acc)+1)
// ---------------------------------------------------------------------------
__global__ void fold_kernel(const float* __restrict__ W_f, const float* __restrict__ b_f,
                            const float* __restrict__ W_ih, const float* __restrict__ W_hh,
                            const float* __restrict__ b_ih,
                            _Float16* __restrict__ Wc16, _Float16* __restrict__ Whh16,
                            float* __restrict__ b_c) {
  const int r = blockIdx.x;    // 0..383
  const int i = threadIdx.x;   // 0..127
  const float scale = (r < 256) ? -1.4426950408889634f : 2.8853900817779268f;
  const float* wih = W_ih + r * HDIM;
  float acc = 0.f;
  for (int h = 0; h < HDIM; ++h) acc = fmaf(wih[h], W_f[h * HDIM + i], acc);
  Wc16[r * HDIM + i]  = (_Float16)(acc * scale);
  Whh16[r * HDIM + i] = (_Float16)(W_hh[r * HDIM + i] * scale);
  if (i == 0) {
    float bb = b_ih[r];
    for (int h = 0; h < HDIM; ++h) bb = fmaf(wih[h], b_f[h], bb);
    b_c[r] = bb;
  }
}

// ---------------------------------------------------------------------------
// Fused GRU, f16 MFMA, FAT-WAVE geometry: 4 waves/block, wave wv owns 32
// j-columns (2 j-tiles of 16) -> halves per-walk LDS traffic (the former
// 8-wave layout had every wave re-reading the full x/h tiles). Weights: 48
// frags = 192 VGPR persistent. 1 wave/SIMD; grid 512 blocks = 2 rounds.
// Lane (g,l15): gates for j = wv*32 + jt*16 + 4g + {0..3}, walk = mt*16+l15.
// LDS tiles XOR-swizzled on the 16B-chunk index (chunk ^= row&7), same
// scheme verified in rounds 5-8. Biases enter via MFMA C-in at kt==0.
// In-step T14 x-prefetch: gather loads issue before the 96-MFMA block and
// are converted/written to LDS after it (latency hidden under MFMAs).
// ---------------------------------------------------------------------------
__global__ __launch_bounds__(NTHR, 1)
void gru_kernel(const float* __restrict__ x, const int* __restrict__ walks,
                const _Float16* __restrict__ Wc16, const _Float16* __restrict__ Whh16,
                const float* __restrict__ b_c, const float* __restrict__ b_hh,
                float* __restrict__ out) {
  __shared__ _Float16 hbuf[2][WPB][HDIM];
  __shared__ _Float16 xbuf[2][WPB][HDIM];
  __shared__ int      nodes[TLEN][WPB];

  const int tid  = threadIdx.x;
  const int lane = tid & 63;
  const int wv   = tid >> 6;        // 0..3 : 32-j-column group
  const int g    = lane >> 4;       // 0..3 : k-chunk / j-quad
  const int l15  = lane & 15;
  const int walk0 = blockIdx.x * WPB;

  for (int idx = tid; idx < TLEN * WPB; idx += NTHR)
    nodes[idx >> 5][idx & 31] = walks[(walk0 + (idx & 31)) * TLEN + (idx >> 5)];
  for (int idx = tid; idx < WPB * HDIM; idx += NTHR)
    hbuf[0][0][idx] = (_Float16)0.f;

  // ---- persistent weight fragments: 6 matrices x 2 j-tiles x 4 kt = 192 VGPR ----
  f16x8 wrx[2][4], wrh[2][4], wzx[2][4], wzh[2][4], wnx[2][4], wnh[2][4];
#pragma unroll
  for (int jt = 0; jt < 2; ++jt) {
    const int jw = wv * 32 + jt * 16 + l15;
#pragma unroll
    for (int kt = 0; kt < 4; ++kt) {
      const int koff = kt * 32 + g * 8;
      wrx[jt][kt] = *(const f16x8*)(Wc16  + (size_t)(jw)       * HDIM + koff);
      wzx[jt][kt] = *(const f16x8*)(Wc16  + (size_t)(128 + jw) * HDIM + koff);
      wnx[jt][kt] = *(const f16x8*)(Wc16  + (size_t)(256 + jw) * HDIM + koff);
      wrh[jt][kt] = *(const f16x8*)(Whh16 + (size_t)(jw)       * HDIM + koff);
      wzh[jt][kt] = *(const f16x8*)(Whh16 + (size_t)(128 + jw) * HDIM + koff);
      wnh[jt][kt] = *(const f16x8*)(Whh16 + (size_t)(256 + jw) * HDIM + koff);
    }
  }
  // ---- biases (scaled), per j-tile, used as MFMA C-in ----
  const float NEG_L2E = -1.4426950408889634f;
  const float TWO_L2E =  2.8853900817779268f;
  f32x4 br4[2], bz4[2], bxn4[2], bhn4[2];
#pragma unroll
  for (int jt = 0; jt < 2; ++jt) {
    const int j0 = wv * 32 + jt * 16 + 4 * g;
    br4[jt]  = NEG_L2E * (*(const f32x4*)&b_c[j0]       + *(const f32x4*)&b_hh[j0]);
    bz4[jt]  = NEG_L2E * (*(const f32x4*)&b_c[128 + j0] + *(const f32x4*)&b_hh[128 + j0]);
    bxn4[jt] = TWO_L2E * (*(const f32x4*)&b_c[256 + j0]);
    bhn4[jt] = TWO_L2E * (*(const f32x4*)&b_hh[256 + j0]);
  }

  f32x4 hprev[2][2];   // [jt][mt]
#pragma unroll
  for (int jt = 0; jt < 2; ++jt) { hprev[jt][0] = 0.f; hprev[jt][1] = 0.f; }

  // ---- swizzled LDS offsets (f16-element units) ----
  int voffs[4];
#pragma unroll
  for (int kt = 0; kt < 4; ++kt)
    voffs[kt] = l15 * HDIM + ((((kt * 4 + g) ^ (l15 & 7))) << 3);
  // x staging: 256 thr, row = tid>>3 (32 rows), 16-f32 chunk sc8 = tid&7
  const int srow = tid >> 3;
  const int sc8  = tid & 7;
  const int xw0  = srow * HDIM + (((2 * sc8)     ^ (srow & 7)) << 3);
  const int xw1  = srow * HDIM + (((2 * sc8 + 1) ^ (srow & 7)) << 3);
  // h write: row l15 (+16 rows for mt=1), chunk = 4wv+2jt+(g>>1), half g&1
  int hw[2];
#pragma unroll
  for (int jt = 0; jt < 2; ++jt)
    hw[jt] = l15 * HDIM + (((4 * wv + 2 * jt + (g >> 1)) ^ (l15 & 7)) << 3) + ((g & 1) << 2);

  __syncthreads();   // nodes + hbuf[0] zeros visible

  // ---- prologue: stage x[0] into xbuf[0] ----
  {
    const unsigned off = ((unsigned)nodes[0][srow] << 7) + sc8 * 16u;
    const f32x4 a0 = *(const f32x4*)(x + off);
    const f32x4 a1 = *(const f32x4*)(x + off + 4);
    const f32x4 a2 = *(const f32x4*)(x + off + 8);
    const f32x4 a3 = *(const f32x4*)(x + off + 12);
    H8 v0, v1;
    v0.p.a = __builtin_amdgcn_cvt_pkrtz(a0.x, a0.y);
    v0.p.b = __builtin_amdgcn_cvt_pkrtz(a0.z, a0.w);
    v0.p.c = __builtin_amdgcn_cvt_pkrtz(a1.x, a1.y);
    v0.p.d = __builtin_amdgcn_cvt_pkrtz(a1.z, a1.w);
    v1.p.a = __builtin_amdgcn_cvt_pkrtz(a2.x, a2.y);
    v1.p.b = __builtin_amdgcn_cvt_pkrtz(a2.z, a2.w);
    v1.p.c = __builtin_amdgcn_cvt_pkrtz(a3.x, a3.y);
    v1.p.d = __builtin_amdgcn_cvt_pkrtz(a3.z, a3.w);
    *(f16x8*)(&xbuf[0][0][0] + xw0) = v0.v;
    *(f16x8*)(&xbuf[0][0][0] + xw1) = v1.v;
  }
  __syncthreads();

#pragma unroll 1
  for (int t = 0; t < TLEN; ++t) {
    const int cur = t & 1;
    const _Float16* xb = &xbuf[cur][0][0];
    const _Float16* hb = &hbuf[cur][0][0];

    // 1. issue gather for x[t+1] (consumed after the MFMA block)
    const bool have = (t + 1 < TLEN);
    const int tn = have ? t + 1 : t;
    const unsigned offn = ((unsigned)nodes[tn][srow] << 7) + sc8 * 16u;
    const f32x4 a0 = *(const f32x4*)(x + offn);
    const f32x4 a1 = *(const f32x4*)(x + offn + 4);
    const f32x4 a2 = *(const f32x4*)(x + offn + 8);
    const f32x4 a3 = *(const f32x4*)(x + offn + 12);

    // 2. 96 MFMAs: B-frags (activations) read once, reused across 2 j-tiles
    f32x4 ar[2][2], az[2][2], an[2][2], ah2[2][2];
#pragma unroll
    for (int kt = 0; kt < 4; ++kt) {
      const f16x8 ax0 = *(const f16x8*)(xb + voffs[kt]);
      const f16x8 ax1 = *(const f16x8*)(xb + voffs[kt] + 16 * HDIM);
      const f16x8 ah0 = *(const f16x8*)(hb + voffs[kt]);
      const f16x8 ah1 = *(const f16x8*)(hb + voffs[kt] + 16 * HDIM);
#pragma unroll
      for (int jt = 0; jt < 2; ++jt) {
        ar[jt][0]  = __builtin_amdgcn_mfma_f32_16x16x32_f16(wrx[jt][kt], ax0, kt ? ar[jt][0]  : br4[jt],  0,0,0);
        ar[jt][1]  = __builtin_amdgcn_mfma_f32_16x16x32_f16(wrx[jt][kt], ax1, kt ? ar[jt][1]  : br4[jt],  0,0,0);
        ar[jt][0]  = __builtin_amdgcn_mfma_f32_16x16x32_f16(wrh[jt][kt], ah0, ar[jt][0],  0,0,0);
        ar[jt][1]  = __builtin_amdgcn_mfma_f32_16x16x32_f16(wrh[jt][kt], ah1, ar[jt][1],  0,0,0);
        az[jt][0]  = __builtin_amdgcn_mfma_f32_16x16x32_f16(wzx[jt][kt], ax0, kt ? az[jt][0]  : bz4[jt],  0,0,0);
        az[jt][1]  = __builtin_amdgcn_mfma_f32_16x16x32_f16(wzx[jt][kt], ax1, kt ? az[jt][1]  : bz4[jt],  0,0,0);
        az[jt][0]  = __builtin_amdgcn_mfma_f32_16x16x32_f16(wzh[jt][kt], ah0, az[jt][0],  0,0,0);
        az[jt][1]  = __builtin_amdgcn_mfma_f32_16x16x32_f16(wzh[jt][kt], ah1, az[jt][1],  0,0,0);
        an[jt][0]  = __builtin_amdgcn_mfma_f32_16x16x32_f16(wnx[jt][kt], ax0, kt ? an[jt][0]  : bxn4[jt], 0,0,0);
        an[jt][1]  = __builtin_amdgcn_mfma_f32_16x16x32_f16(wnx[jt][kt], ax1, kt ? an[jt][1]  : bxn4[jt], 0,0,0);
        ah2[jt][0] = __builtin_amdgcn_mfma_f32_16x16x32_f16(wnh[jt][kt], ah0, kt ? ah2[jt][0] : bhn4[jt], 0,0,0);
        ah2[jt][1] = __builtin_amdgcn_mfma_f32_16x16x32_f16(wnh[jt][kt], ah1, kt ? ah2[jt][1] : bhn4[jt], 0,0,0);
      }
    }

    // 3. convert + write x[t+1] into the other buffer (loads now complete)
    if (have) {
      H8 v0, v1;
      v0.p.a = __builtin_amdgcn_cvt_pkrtz(a0.x, a0.y);
      v0.p.b = __builtin_amdgcn_cvt_pkrtz(a0.z, a0.w);
      v0.p.c = __builtin_amdgcn_cvt_pkrtz(a1.x, a1.y);
      v0.p.d = __builtin_amdgcn_cvt_pkrtz(a1.z, a1.w);
      v1.p.a = __builtin_amdgcn_cvt_pkrtz(a2.x, a2.y);
      v1.p.b = __builtin_amdgcn_cvt_pkrtz(a2.z, a2.w);
      v1.p.c = __builtin_amdgcn_cvt_pkrtz(a3.x, a3.y);
      v1.p.d = __builtin_amdgcn_cvt_pkrtz(a3.z, a3.w);
      *(f16x8*)(&xbuf[cur ^ 1][0][0] + xw0) = v0.v;
      *(f16x8*)(&xbuf[cur ^ 1][0][0] + xw1) = v1.v;
    }

    // 4. gates (lane-local, scaled-exp2 forms) + h writeback
#pragma unroll
    for (int jt = 0; jt < 2; ++jt)
#pragma unroll
      for (int mt = 0; mt < 2; ++mt) {
        f32x4 hn;
#pragma unroll
        for (int r = 0; r < 4; ++r) {
          const float rv = __builtin_amdgcn_rcpf(1.f + __builtin_amdgcn_exp2f(ar[jt][mt][r]));
          const float zv = __builtin_amdgcn_rcpf(1.f + __builtin_amdgcn_exp2f(az[jt][mt][r]));
          const float en = __builtin_amdgcn_exp2f(fmaf(rv, ah2[jt][mt][r], an[jt][mt][r]));
          const float nv = fmaf(-2.f, __builtin_amdgcn_rcpf(en + 1.f), 1.f);
          hn[r] = fmaf(zv, hprev[jt][mt][r] - nv, nv);
        }
        hprev[jt][mt] = hn;
        H4 hp;
        hp.p.lo = __builtin_amdgcn_cvt_pkrtz(hn[0], hn[1]);
        hp.p.hi = __builtin_amdgcn_cvt_pkrtz(hn[2], hn[3]);
        *(f16x4*)(&hbuf[cur ^ 1][0][0] + hw[jt] + mt * 16 * HDIM) = hp.v;
      }

    __syncthreads();
  }

  // ---- final h: lane holds j0..j0+3 for (jt, walks l15 / 16+l15) ----
#pragma unroll
  for (int jt = 0; jt < 2; ++jt)
#pragma unroll
    for (int mt = 0; mt < 2; ++mt) {
      float4 o = make_float4(hprev[jt][mt][0], hprev[jt][mt][1], hprev[jt][mt][2], hprev[jt][mt][3]);
      *(float4*)&out[(size_t)(walk0 + mt * 16 + l15) * HDIM + wv * 32 + jt * 16 + 4 * g] = o;
    }
}

extern "C" void kernel_launch(void* const* d_in, const int* in_sizes, int n_in,
                              void* d_out, int out_size, void* d_ws, size_t ws_size,
                              hipStream_t stream) {
  const float* x     = (const float*)d_in[0];
  const int*   walks = (const int*)  d_in[1];
  const float* W_f   = (const float*)d_in[2];
  const float* b_f   = (const float*)d_in[3];
  const float* W_ih  = (const float*)d_in[4];
  const float* W_hh  = (const float*)d_in[5];
  const float* b_ih  = (const float*)d_in[6];
  const float* b_hh  = (const float*)d_in[7];
  float* out = (float*)d_out;

  _Float16* Wc16  = (_Float16*)d_ws;                 // 384*128 f16
  _Float16* Whh16 = Wc16 + 384 * HDIM;               // 384*128 f16
  float*    b_c   = (float*)(Whh16 + 384 * HDIM);    // 384 f32

  fold_kernel<<<3 * HDIM, HDIM, 0, stream>>>(W_f, b_f, W_ih, W_hh, b_ih, Wc16, Whh16, b_c);
  gru_kernel<<<NWALKS / WPB, NTHR, 0, stream>>>(x, walks, Wc16, Whh16, b_c, b_hh, out);
}

// Round 10
// 97.307 us; speedup vs baseline: 1.0987x; 1.0987x over previous
//
#include <hip/hip_runtime.h>
#include <cstddef>

#define NWALKS 16384
#define TLEN   20
#define HDIM   128
#define WPB    16     // walks per block (1 m-tile) -- occupancy experiment
#define NTHR   512    // 8 waves

typedef __attribute__((ext_vector_type(8))) _Float16 f16x8;
typedef __attribute__((ext_vector_type(4))) _Float16 f16x4;
typedef __attribute__((ext_vector_type(2))) __fp16   h16x2;   // cvt_pkrtz result type
typedef __attribute__((ext_vector_type(4))) float    f32x4;

union H4 { f16x4 v; struct { h16x2 lo, hi; } p; };

// ---------------------------------------------------------------------------
// fold: Wc16 = f16(scale_row * (W_ih @ W_f)), Whh16 = f16(scale_row * W_hh),
// b_c = W_ih@b_f + b_ih (unscaled; scaled at load in gru_kernel).
//   r,z rows (0..255):  * -log2(e)   -> sigmoid(v) = rcp(1 + exp2(acc))
//   n  rows (256..383): * +2*log2(e) -> tanh(v)    = 1 - 2*rcp(exp2(acc)+1)
// ---------------------------------------------------------------------------
__global__ void fold_kernel(const float* __restrict__ W_f, const float* __restrict__ b_f,
                            const float* __restrict__ W_ih, const float* __restrict__ W_hh,
                            const float* __restrict__ b_ih,
                            _Float16* __restrict__ Wc16, _Float16* __restrict__ Whh16,
                            float* __restrict__ b_c) {
  const int r = blockIdx.x;    // 0..383
  const int i = threadIdx.x;   // 0..127
  const float scale = (r < 256) ? -1.4426950408889634f : 2.8853900817779268f;
  const float* wih = W_ih + r * HDIM;
  float acc = 0.f;
  for (int h = 0; h < HDIM; ++h) acc = fmaf(wih[h], W_f[h * HDIM + i], acc);
  Wc16[r * HDIM + i]  = (_Float16)(acc * scale);
  Whh16[r * HDIM + i] = (_Float16)(W_hh[r * HDIM + i] * scale);
  if (i == 0) {
    float bb = b_ih[r];
    for (int h = 0; h < HDIM; ++h) bb = fmaf(wih[h], b_f[h], bb);
    b_c[r] = bb;
  }
}

// ---------------------------------------------------------------------------
// Fused GRU, f16 MFMA. Same verified per-wave geometry as rounds 5-8 (wave wv
// owns gate columns [wv*16,wv*16+16); lane (g,l15): j = wv*16+4g+{0..3},
// walk = l15), but ONE m-tile per block (WPB=16) -> LDS 17.7 KB, acc 16 regs,
// grid 1024. Goal: multiple independent blocks per CU (de-convoyed barrier
// groups + full SIMD occupancy). Weights persist in 24 frags; biases via
// MFMA C-in; LDS XOR-swizzled (chunk ^= row&7); raw lgkm-only barrier.
// ---------------------------------------------------------------------------
__global__ __launch_bounds__(NTHR, 2)
void gru_kernel(const float* __restrict__ x, const int* __restrict__ walks,
                const _Float16* __restrict__ Wc16, const _Float16* __restrict__ Whh16,
                const float* __restrict__ b_c, const float* __restrict__ b_hh,
                float* __restrict__ out) {
  __shared__ _Float16 hbuf[2][WPB][HDIM];
  __shared__ _Float16 xbuf[2][WPB][HDIM];
  __shared__ int      nodes[TLEN][WPB];

  const int tid  = threadIdx.x;
  const int lane = tid & 63;
  const int wv   = tid >> 6;        // 0..7 : j-tile
  const int g    = lane >> 4;       // 0..3 : k-chunk / j-quad
  const int l15  = lane & 15;       // walk within block
  const int jw   = wv * 16 + l15;   // weight row for frag loads
  const int j0   = wv * 16 + 4 * g; // this lane's 4 j-columns
  const int walk0 = blockIdx.x * WPB;

  for (int idx = tid; idx < TLEN * WPB; idx += NTHR)
    nodes[idx >> 4][idx & 15] = walks[(walk0 + (idx & 15)) * TLEN + (idx >> 4)];
  for (int idx = tid; idx < WPB * HDIM; idx += NTHR)
    hbuf[0][0][idx] = (_Float16)0.f;   // zero fill: swizzle-invariant

  // ---- persistent weight fragments (A-operand), 24 frags ----
  f16x8 wrx[4], wrh[4], wzx[4], wzh[4], wnx[4], wnh[4];
#pragma unroll
  for (int kt = 0; kt < 4; ++kt) {
    const int koff = kt * 32 + g * 8;
    wrx[kt] = *(const f16x8*)(Wc16  + (size_t)(jw)       * HDIM + koff);
    wzx[kt] = *(const f16x8*)(Wc16  + (size_t)(128 + jw) * HDIM + koff);
    wnx[kt] = *(const f16x8*)(Wc16  + (size_t)(256 + jw) * HDIM + koff);
    wrh[kt] = *(const f16x8*)(Whh16 + (size_t)(jw)       * HDIM + koff);
    wzh[kt] = *(const f16x8*)(Whh16 + (size_t)(128 + jw) * HDIM + koff);
    wnh[kt] = *(const f16x8*)(Whh16 + (size_t)(256 + jw) * HDIM + koff);
  }
  // ---- biases (scaled), used as MFMA C-in on kt==0 ----
  const float NEG_L2E = -1.4426950408889634f;
  const float TWO_L2E =  2.8853900817779268f;
  const f32x4 br4  = NEG_L2E * (*(const f32x4*)&b_c[j0]       + *(const f32x4*)&b_hh[j0]);
  const f32x4 bz4  = NEG_L2E * (*(const f32x4*)&b_c[128 + j0] + *(const f32x4*)&b_hh[128 + j0]);
  const f32x4 bxn4 = TWO_L2E * (*(const f32x4*)&b_c[256 + j0]);
  const f32x4 bhn4 = TWO_L2E * (*(const f32x4*)&b_hh[256 + j0]);

  f32x4 hprev;
  hprev = 0.f;

  // ---- swizzled LDS offsets (f16-element units) ----
  int voffs[4];
#pragma unroll
  for (int kt = 0; kt < 4; ++kt)
    voffs[kt] = l15 * HDIM + ((((kt * 4 + g) ^ (l15 & 7))) << 3);
  // x staging: 16 rows x 32 threads/row, each thread one f32x4 (8B f16 write)
  const int srow = tid >> 5;        // 0..15
  const int sc4  = tid & 31;        // f32x4 chunk within row
  const int xw   = srow * HDIM + (((sc4 >> 1) ^ (srow & 7)) << 3) + ((sc4 & 1) << 2);
  // h write: row l15, chunk 2wv+(g>>1), half (g&1)
  const int hw   = l15 * HDIM + (((2 * wv + (g >> 1)) ^ (l15 & 7)) << 3) + ((g & 1) << 2);

  __syncthreads();   // nodes + hbuf[0] zeros visible

  // ---- prologue: stage x[0] into xbuf[0]; load x[1] into regs ----
  {
    const unsigned off0 = ((unsigned)nodes[0][srow] << 7) + sc4 * 4u;
    const f32x4 a = *(const f32x4*)(x + off0);
    H4 v;
    v.p.lo = __builtin_amdgcn_cvt_pkrtz(a.x, a.y);
    v.p.hi = __builtin_amdgcn_cvt_pkrtz(a.z, a.w);
    *(f16x4*)(&xbuf[0][0][0] + xw) = v.v;
  }
  f32x4 PA, PB;
  {
    const unsigned off1 = ((unsigned)nodes[1][srow] << 7) + sc4 * 4u;
    PA = *(const f32x4*)(x + off1);
  }
  __syncthreads();   // xbuf[0] + hbuf[0] visible

#define STEP(T, CUR, NXT, P, N)                                                   \
  {                                                                               \
    /* 1. issue gather for x[T+2]; stays in flight across the raw barrier */      \
    const int tn = ((T) + 2 < TLEN) ? (T) + 2 : TLEN - 1;                         \
    const unsigned offn = ((unsigned)nodes[tn][srow] << 7) + sc4 * 4u;            \
    N = *(const f32x4*)(x + offn);                                                \
    /* 2. 24 MFMAs; bias enters as C-in on kt==0 */                               \
    const _Float16* xb = &xbuf[CUR][0][0];                                        \
    const _Float16* hb = &hbuf[CUR][0][0];                                        \
    f32x4 ar, az, an, ah2;                                                        \
    __builtin_amdgcn_s_setprio(1);                                                \
    _Pragma("unroll")                                                             \
    for (int kt = 0; kt < 4; ++kt) {                                              \
      const f16x8 ax = *(const f16x8*)(xb + voffs[kt]);                           \
      const f16x8 ah = *(const f16x8*)(hb + voffs[kt]);                           \
      ar  = __builtin_amdgcn_mfma_f32_16x16x32_f16(wrx[kt], ax, kt ? ar  : br4,  0,0,0); \
      ar  = __builtin_amdgcn_mfma_f32_16x16x32_f16(wrh[kt], ah, ar,  0,0,0);      \
      az  = __builtin_amdgcn_mfma_f32_16x16x32_f16(wzx[kt], ax, kt ? az  : bz4,  0,0,0); \
      az  = __builtin_amdgcn_mfma_f32_16x16x32_f16(wzh[kt], ah, az,  0,0,0);      \
      an  = __builtin_amdgcn_mfma_f32_16x16x32_f16(wnx[kt], ax, kt ? an  : bxn4, 0,0,0); \
      ah2 = __builtin_amdgcn_mfma_f32_16x16x32_f16(wnh[kt], ah, kt ? ah2 : bhn4, 0,0,0); \
    }                                                                             \
    __builtin_amdgcn_s_setprio(0);                                                \
    /* 3. write x[T+1] (loaded last step) into the other buffer */                \
    {                                                                             \
      H4 v;                                                                       \
      v.p.lo = __builtin_amdgcn_cvt_pkrtz(P.x, P.y);                              \
      v.p.hi = __builtin_amdgcn_cvt_pkrtz(P.z, P.w);                              \
      *(f16x4*)(&xbuf[NXT][0][0] + xw) = v.v;                                     \
    }                                                                             \
    /* 4. gates (lane-local, scaled-exp2 forms) + h writeback (b64) */            \
    {                                                                             \
      f32x4 hn;                                                                   \
      _Pragma("unroll")                                                           \
      for (int r = 0; r < 4; ++r) {                                               \
        const float rv = __builtin_amdgcn_rcpf(1.f + __builtin_amdgcn_exp2f(ar[r])); \
        const float zv = __builtin_amdgcn_rcpf(1.f + __builtin_amdgcn_exp2f(az[r])); \
        const float en = __builtin_amdgcn_exp2f(fmaf(rv, ah2[r], an[r]));         \
        const float nv = fmaf(-2.f, __builtin_amdgcn_rcpf(en + 1.f), 1.f);        \
        hn[r] = fmaf(zv, hprev[r] - nv, nv);                                      \
      }                                                                           \
      hprev = hn;                                                                 \
      H4 hp;                                                                      \
      hp.p.lo = __builtin_amdgcn_cvt_pkrtz(hn[0], hn[1]);                         \
      hp.p.hi = __builtin_amdgcn_cvt_pkrtz(hn[2], hn[3]);                         \
      *(f16x4*)(&hbuf[NXT][0][0] + hw) = hp.v;                                    \
    }                                                                             \
    /* 5. raw barrier: LDS drain only; global prefetch stays in flight */         \
    __builtin_amdgcn_sched_barrier(0);                                            \
    asm volatile("s_waitcnt lgkmcnt(0)" ::: "memory");                            \
    __builtin_amdgcn_s_barrier();                                                 \
    __builtin_amdgcn_sched_barrier(0);                                            \
  }

#pragma unroll 1
  for (int tt = 0; tt < TLEN; tt += 2) {
    STEP(tt,     0, 1, PA, PB)
    STEP(tt + 1, 1, 0, PB, PA)
  }
#undef STEP

  // ---- final h: lane holds j0..j0+3 for walk l15 ----
  {
    float4 o = make_float4(hprev[0], hprev[1], hprev[2], hprev[3]);
    *(float4*)&out[(size_t)(walk0 + l15) * HDIM + j0] = o;
  }
}

extern "C" void kernel_launch(void* const* d_in, const int* in_sizes, int n_in,
                              void* d_out, int out_size, void* d_ws, size_t ws_size,
                              hipStream_t stream) {
  const float* x     = (const float*)d_in[0];
  const int*   walks = (const int*)  d_in[1];
  const float* W_f   = (const float*)d_in[2];
  const float* b_f   = (const float*)d_in[3];
  const float* W_ih  = (const float*)d_in[4];
  const float* W_hh  = (const float*)d_in[5];
  const float* b_ih  = (const float*)d_in[6];
  const float* b_hh  = (const float*)d_in[7];
  float* out = (float*)d_out;

  _Float16* Wc16  = (_Float16*)d_ws;                 // 384*128 f16
  _Float16* Whh16 = Wc16 + 384 * HDIM;               // 384*128 f16
  float*    b_c   = (float*)(Whh16 + 384 * HDIM);    // 384 f32

  fold_kernel<<<3 * HDIM, HDIM, 0, stream>>>(W_f, b_f, W_ih, W_hh, b_ih, Wc16, Whh16, b_c);
  gru_kernel<<<NWALKS / WPB, NTHR, 0, stream>>>(x, walks, Wc16, Whh16, b_c, b_hh, out);
}

// Round 11
// 80.344 us; speedup vs baseline: 1.3306x; 1.2111x over previous
//
#include <hip/hip_runtime.h>
#include <cstddef>

#define NWALKS 16384
#define TLEN   20
#define HDIM   128
#define WPB    64     // 2 independent pipelines of 32 walks
#define NTHR   512    // 8 waves

typedef __attribute__((ext_vector_type(8))) _Float16 f16x8;
typedef __attribute__((ext_vector_type(4))) _Float16 f16x4;
typedef __attribute__((ext_vector_type(2))) __fp16   h16x2;   // cvt_pkrtz result type
typedef __attribute__((ext_vector_type(4))) float    f32x4;

union H4 { f16x4 v; struct { h16x2 lo, hi; } p; };

// ---------------------------------------------------------------------------
// fold: Wc16 = f16(scale_row * (W_ih @ W_f)), Whh16 = f16(scale_row * W_hh),
// b_c = W_ih@b_f + b_ih (unscaled; scaled at load in gru_kernel).
//   r,z rows (0..255):  * -log2(e)   -> sigmoid(v) = rcp(1 + exp2(acc))
//   n  rows (256..383): * +2*log2(e) -> tanh(v)    = 1 - 2*rcp(exp2(acc)+1)
// ---------------------------------------------------------------------------
__global__ void fold_kernel(const float* __restrict__ W_f, const float* __restrict__ b_f,
                            const float* __restrict__ W_ih, const float* __restrict__ W_hh,
                            const float* __restrict__ b_ih,
                            _Float16* __restrict__ Wc16, _Float16* __restrict__ Whh16,
                            float* __restrict__ b_c) {
  const int r = blockIdx.x;    // 0..383
  const int i = threadIdx.x;   // 0..127
  const float scale = (r < 256) ? -1.4426950408889634f : 2.8853900817779268f;
  const float* wih = W_ih + r * HDIM;
  float acc = 0.f;
  for (int h = 0; h < HDIM; ++h) acc = fmaf(wih[h], W_f[h * HDIM + i], acc);
  Wc16[r * HDIM + i]  = (_Float16)(acc * scale);
  Whh16[r * HDIM + i] = (_Float16)(W_hh[r * HDIM + i] * scale);
  if (i == 0) {
    float bb = b_ih[r];
    for (int h = 0; h < HDIM; ++h) bb = fmaf(wih[h], b_f[h], bb);
    b_c[r] = bb;
  }
}

// ---------------------------------------------------------------------------
// Fused GRU, f16 MFMA, DUAL-PIPELINE: two independent 32-walk GRU pipelines
// (A,B) per block, phase-shifted by half a step, so every MFMA cluster
// overlaps the other pipeline's gate/staging VALU work (the round-4..10
// single-pipeline kernels serialized phases: sum-of-pipes ~84us).
//   half1(k): gather xA[k+1] | A-MFMA(k)  || B-gates(k-1)+writes | bar
//   half2(k): gather xB[k+1] | B-MFMA(k)  || A-gates(k)+writes   | bar
// Single-buffered x/h per pipeline (all writes barrier-separated from reads).
// Per-wave geometry unchanged from rounds 5-8 (verified): wave wv owns gate
// columns [wv*16,wv*16+16); lane (g,l15): j = wv*16+4g+{0..3}, walk = mt*16
// + l15. Weights persist in 96 regs; biases via MFMA C-in at kt==0; LDS
// XOR-swizzled (16B chunk ^= row&7); raw lgkm-only barriers.
// ---------------------------------------------------------------------------
__global__ __launch_bounds__(NTHR, 1)
void gru_kernel(const float* __restrict__ x, const int* __restrict__ walks,
                const _Float16* __restrict__ Wc16, const _Float16* __restrict__ Whh16,
                const float* __restrict__ b_c, const float* __restrict__ b_hh,
                float* __restrict__ out) {
  __shared__ _Float16 hbufA[32][HDIM];
  __shared__ _Float16 xbufA[32][HDIM];
  __shared__ _Float16 hbufB[32][HDIM];
  __shared__ _Float16 xbufB[32][HDIM];
  __shared__ int      nodesA[TLEN][32];
  __shared__ int      nodesB[TLEN][32];

  const int tid  = threadIdx.x;
  const int lane = tid & 63;
  const int wv   = tid >> 6;        // 0..7 : j-tile
  const int g    = lane >> 4;       // 0..3 : k-chunk / j-quad
  const int l15  = lane & 15;
  const int jw   = wv * 16 + l15;   // weight row for frag loads
  const int j0   = wv * 16 + 4 * g; // this lane's 4 j-columns
  const int walk0 = blockIdx.x * WPB;

  for (int idx = tid; idx < TLEN * 32; idx += NTHR) {
    nodesA[idx >> 5][idx & 31] = walks[(walk0 +      (idx & 31)) * TLEN + (idx >> 5)];
    nodesB[idx >> 5][idx & 31] = walks[(walk0 + 32 + (idx & 31)) * TLEN + (idx >> 5)];
  }
  for (int idx = tid; idx < 32 * HDIM; idx += NTHR) {
    hbufA[0][idx] = (_Float16)0.f;
    hbufB[0][idx] = (_Float16)0.f;
  }

  // ---- persistent weight fragments (A-operand), 96 VGPR ----
  f16x8 wrx[4], wrh[4], wzx[4], wzh[4], wnx[4], wnh[4];
#pragma unroll
  for (int kt = 0; kt < 4; ++kt) {
    const int koff = kt * 32 + g * 8;
    wrx[kt] = *(const f16x8*)(Wc16  + (size_t)(jw)       * HDIM + koff);
    wzx[kt] = *(const f16x8*)(Wc16  + (size_t)(128 + jw) * HDIM + koff);
    wnx[kt] = *(const f16x8*)(Wc16  + (size_t)(256 + jw) * HDIM + koff);
    wrh[kt] = *(const f16x8*)(Whh16 + (size_t)(jw)       * HDIM + koff);
    wzh[kt] = *(const f16x8*)(Whh16 + (size_t)(128 + jw) * HDIM + koff);
    wzh[kt] = *(const f16x8*)(Whh16 + (size_t)(128 + jw) * HDIM + koff);
    wnh[kt] = *(const f16x8*)(Whh16 + (size_t)(256 + jw) * HDIM + koff);
  }
  // ---- biases (scaled), used as MFMA C-in on kt==0 ----
  const float NEG_L2E = -1.4426950408889634f;
  const float TWO_L2E =  2.8853900817779268f;
  const f32x4 br4  = NEG_L2E * (*(const f32x4*)&b_c[j0]       + *(const f32x4*)&b_hh[j0]);
  const f32x4 bz4  = NEG_L2E * (*(const f32x4*)&b_c[128 + j0] + *(const f32x4*)&b_hh[128 + j0]);
  const f32x4 bxn4 = TWO_L2E * (*(const f32x4*)&b_c[256 + j0]);
  const f32x4 bhn4 = TWO_L2E * (*(const f32x4*)&b_hh[256 + j0]);

  f32x4 hprevA[2], hprevB[2];
  hprevA[0] = 0.f; hprevA[1] = 0.f;
  hprevB[0] = 0.f; hprevB[1] = 0.f;

  // ---- swizzled LDS offsets (f16-element units) ----
  int voffs[4];
#pragma unroll
  for (int kt = 0; kt < 4; ++kt)
    voffs[kt] = l15 * HDIM + ((((kt * 4 + g) ^ (l15 & 7))) << 3);
  const int srow = tid >> 4;   // 0..31
  const int sc   = tid & 15;   // 8-float chunk
  const int xw   = srow * HDIM + ((sc ^ (srow & 7)) << 3);
  const int hw   = l15 * HDIM + (((2 * wv + (g >> 1)) ^ (l15 & 7)) << 3) + ((g & 1) << 2);

  // accumulators (live across halves)
  f32x4 arA[2], azA[2], anA[2], ah2A[2];
  f32x4 arB[2], azB[2], anB[2], ah2B[2];
  f32x4 GA0, GA1, GB0, GB1;   // gathered x rows in flight

  __syncthreads();   // nodes + zero h visible

  // ---- prologue: stage x_A[0], x_B[0] directly ----
  {
    const unsigned offA = ((unsigned)nodesA[0][srow] << 7) + sc * 8u;
    const unsigned offB = ((unsigned)nodesB[0][srow] << 7) + sc * 8u;
    const f32x4 a0 = *(const f32x4*)(x + offA);
    const f32x4 a1 = *(const f32x4*)(x + offA + 4);
    const f32x4 b0 = *(const f32x4*)(x + offB);
    const f32x4 b1 = *(const f32x4*)(x + offB + 4);
    H4 va, vb, wa, wb;
    va.p.lo = __builtin_amdgcn_cvt_pkrtz(a0.x, a0.y);
    va.p.hi = __builtin_amdgcn_cvt_pkrtz(a0.z, a0.w);
    vb.p.lo = __builtin_amdgcn_cvt_pkrtz(a1.x, a1.y);
    vb.p.hi = __builtin_amdgcn_cvt_pkrtz(a1.z, a1.w);
    wa.p.lo = __builtin_amdgcn_cvt_pkrtz(b0.x, b0.y);
    wa.p.hi = __builtin_amdgcn_cvt_pkrtz(b0.z, b0.w);
    wb.p.lo = __builtin_amdgcn_cvt_pkrtz(b1.x, b1.y);
    wb.p.hi = __builtin_amdgcn_cvt_pkrtz(b1.z, b1.w);
    *(f16x4*)(&xbufA[0][0] + xw)     = va.v;
    *(f16x4*)(&xbufA[0][0] + xw + 4) = vb.v;
    *(f16x4*)(&xbufB[0][0] + xw)     = wa.v;
    *(f16x4*)(&xbufB[0][0] + xw + 4) = wb.v;
  }
  __syncthreads();

#define RAWBAR()                                                                  \
  __builtin_amdgcn_sched_barrier(0);                                              \
  asm volatile("s_waitcnt lgkmcnt(0)" ::: "memory");                              \
  __builtin_amdgcn_s_barrier();                                                   \
  __builtin_amdgcn_sched_barrier(0);

#define GATHER(nodesP, T, G0, G1)                                                 \
  {                                                                               \
    const int tn = ((T) < TLEN) ? (T) : TLEN - 1;                                 \
    const unsigned o = ((unsigned)nodesP[tn][srow] << 7) + sc * 8u;               \
    G0 = *(const f32x4*)(x + o);                                                  \
    G1 = *(const f32x4*)(x + o + 4);                                              \
  }

#define MFMA_BLOCK(xbufP, hbufP, ar, az, an, ah2)                                 \
  {                                                                               \
    const _Float16* xb = &xbufP[0][0];                                            \
    const _Float16* hb = &hbufP[0][0];                                            \
    __builtin_amdgcn_s_setprio(1);                                                \
    _Pragma("unroll")                                                             \
    for (int kt = 0; kt < 4; ++kt) {                                              \
      const f16x8 ax0 = *(const f16x8*)(xb + voffs[kt]);                          \
      const f16x8 ax1 = *(const f16x8*)(xb + voffs[kt] + 16 * HDIM);              \
      const f16x8 ah0 = *(const f16x8*)(hb + voffs[kt]);                          \
      const f16x8 ah1 = *(const f16x8*)(hb + voffs[kt] + 16 * HDIM);              \
      ar[0]  = __builtin_amdgcn_mfma_f32_16x16x32_f16(wrx[kt], ax0, kt ? ar[0]  : br4,  0,0,0); \
      ar[1]  = __builtin_amdgcn_mfma_f32_16x16x32_f16(wrx[kt], ax1, kt ? ar[1]  : br4,  0,0,0); \
      ar[0]  = __builtin_amdgcn_mfma_f32_16x16x32_f16(wrh[kt], ah0, ar[0],  0,0,0); \
      ar[1]  = __builtin_amdgcn_mfma_f32_16x16x32_f16(wrh[kt], ah1, ar[1],  0,0,0); \
      az[0]  = __builtin_amdgcn_mfma_f32_16x16x32_f16(wzx[kt], ax0, kt ? az[0]  : bz4,  0,0,0); \
      az[1]  = __builtin_amdgcn_mfma_f32_16x16x32_f16(wzx[kt], ax1, kt ? az[1]  : bz4,  0,0,0); \
      az[0]  = __builtin_amdgcn_mfma_f32_16x16x32_f16(wzh[kt], ah0, az[0],  0,0,0); \
      az[1]  = __builtin_amdgcn_mfma_f32_16x16x32_f16(wzh[kt], ah1, az[1],  0,0,0); \
      an[0]  = __builtin_amdgcn_mfma_f32_16x16x32_f16(wnx[kt], ax0, kt ? an[0]  : bxn4, 0,0,0); \
      an[1]  = __builtin_amdgcn_mfma_f32_16x16x32_f16(wnx[kt], ax1, kt ? an[1]  : bxn4, 0,0,0); \
      ah2[0] = __builtin_amdgcn_mfma_f32_16x16x32_f16(wnh[kt], ah0, kt ? ah2[0] : bhn4, 0,0,0); \
      ah2[1] = __builtin_amdgcn_mfma_f32_16x16x32_f16(wnh[kt], ah1, kt ? ah2[1] : bhn4, 0,0,0); \
    }                                                                             \
    __builtin_amdgcn_s_setprio(0);                                                \
  }

#define GATES(ar, az, an, ah2, hprevP, hbufP)                                     \
  {                                                                               \
    _Pragma("unroll")                                                             \
    for (int mt = 0; mt < 2; ++mt) {                                              \
      f32x4 hn;                                                                   \
      _Pragma("unroll")                                                           \
      for (int r = 0; r < 4; ++r) {                                               \
        const float rv = __builtin_amdgcn_rcpf(1.f + __builtin_amdgcn_exp2f(ar[mt][r])); \
        const float zv = __builtin_amdgcn_rcpf(1.f + __builtin_amdgcn_exp2f(az[mt][r])); \
        const float en = __builtin_amdgcn_exp2f(fmaf(rv, ah2[mt][r], an[mt][r])); \
        const float nv = fmaf(-2.f, __builtin_amdgcn_rcpf(en + 1.f), 1.f);        \
        hn[r] = fmaf(zv, hprevP[mt][r] - nv, nv);                                 \
      }                                                                           \
      hprevP[mt] = hn;                                                            \
      H4 hp;                                                                      \
      hp.p.lo = __builtin_amdgcn_cvt_pkrtz(hn[0], hn[1]);                         \
      hp.p.hi = __builtin_amdgcn_cvt_pkrtz(hn[2], hn[3]);                         \
      *(f16x4*)(&hbufP[0][0] + hw + mt * 16 * HDIM) = hp.v;                       \
    }                                                                             \
  }

#define XWRITE(xbufP, G0, G1)                                                     \
  {                                                                               \
    H4 lo, hi;                                                                    \
    lo.p.lo = __builtin_amdgcn_cvt_pkrtz(G0.x, G0.y);                             \
    lo.p.hi = __builtin_amdgcn_cvt_pkrtz(G0.z, G0.w);                             \
    hi.p.lo = __builtin_amdgcn_cvt_pkrtz(G1.x, G1.y);                             \
    hi.p.hi = __builtin_amdgcn_cvt_pkrtz(G1.z, G1.w);                             \
    *(f16x4*)(&xbufP[0][0] + xw)     = lo.v;                                      \
    *(f16x4*)(&xbufP[0][0] + xw + 4) = hi.v;                                      \
  }

#pragma unroll 1
  for (int k = 0; k < TLEN; ++k) {
    // ---------- half1: A-MFMA(k) || B-gates(k-1) + B-writes ----------
    GATHER(nodesA, k + 1, GA0, GA1)
    MFMA_BLOCK(xbufA, hbufA, arA, azA, anA, ah2A)
    if (k > 0) {
      GATES(arB, azB, anB, ah2B, hprevB, hbufB)   // h_B[k] -> hbufB
      XWRITE(xbufB, GB0, GB1)                     // x_B[k] -> xbufB
    }
    RAWBAR()
    // ---------- half2: B-MFMA(k) || A-gates(k) + A-writes ----------
    GATHER(nodesB, k + 1, GB0, GB1)
    MFMA_BLOCK(xbufB, hbufB, arB, azB, anB, ah2B)
    GATES(arA, azA, anA, ah2A, hprevA, hbufA)     // h_A[k+1] -> hbufA
    XWRITE(xbufA, GA0, GA1)                       // x_A[k+1] -> xbufA
    RAWBAR()
  }
  // ---------- epilogue: finish B's last step ----------
  GATES(arB, azB, anB, ah2B, hprevB, hbufB)

#undef RAWBAR
#undef GATHER
#undef MFMA_BLOCK
#undef GATES
#undef XWRITE

  // ---- final h: lane holds j0..j0+3 for walks (A: l15/16+l15, B: +32) ----
#pragma unroll
  for (int mt = 0; mt < 2; ++mt) {
    float4 oa = make_float4(hprevA[mt][0], hprevA[mt][1], hprevA[mt][2], hprevA[mt][3]);
    float4 ob = make_float4(hprevB[mt][0], hprevB[mt][1], hprevB[mt][2], hprevB[mt][3]);
    *(float4*)&out[(size_t)(walk0 +      mt * 16 + l15) * HDIM + j0] = oa;
    *(float4*)&out[(size_t)(walk0 + 32 + mt * 16 + l15) * HDIM + j0] = ob;
  }
}

extern "C" void kernel_launch(void* const* d_in, const int* in_sizes, int n_in,
                              void* d_out, int out_size, void* d_ws, size_t ws_size,
                              hipStream_t stream) {
  const float* x     = (const float*)d_in[0];
  const int*   walks = (const int*)  d_in[1];
  const float* W_f   = (const float*)d_in[2];
  const float* b_f   = (const float*)d_in[3];
  const float* W_ih  = (const float*)d_in[4];
  const float* W_hh  = (const float*)d_in[5];
  const float* b_ih  = (const float*)d_in[6];
  const float* b_hh  = (const float*)d_in[7];
  float* out = (float*)d_out;

  _Float16* Wc16  = (_Float16*)d_ws;                 // 384*128 f16
  _Float16* Whh16 = Wc16 + 384 * HDIM;               // 384*128 f16
  float*    b_c   = (float*)(Whh16 + 384 * HDIM);    // 384 f32

  fold_kernel<<<3 * HDIM, HDIM, 0, stream>>>(W_f, b_f, W_ih, W_hh, b_ih, Wc16, Whh16, b_c);
  gru_kernel<<<NWALKS / WPB, NTHR, 0, stream>>>(x, walks, Wc16, Whh16, b_c, b_hh, out);
}